// Round 2
// baseline (13909.474 us; speedup 1.0000x reference)
//
#include <hip/hip_runtime.h>
#include <math.h>

#define BATCH 16
#define SEQ   1024
#define DIM   2048
#define EPS_F 0.1f
#define INV_EPS 10.0f
#define N_ITER 100

typedef short bf16x8 __attribute__((ext_vector_type(8)));
typedef float f32x4  __attribute__((ext_vector_type(4)));

__device__ inline float bf16_to_f(unsigned short u) {
    unsigned int x = ((unsigned int)u) << 16;
    return __uint_as_float(x);
}
__device__ inline unsigned short f_to_bf16(float f) {
    unsigned int x = __float_as_uint(f);
    unsigned int lsb = (x >> 16) & 1u;
    x += 0x7fffu + lsb;               // round-to-nearest-even
    return (unsigned short)(x >> 16);
}

// ---------------- init: v = 1, barriers = 0 ----------------
__global__ void init_uvbar(float* __restrict__ v, unsigned int* __restrict__ bar) {
    int i = blockIdx.x * 256 + threadIdx.x;
    v[i] = 1.0f;                       // grid 64 x 256 = 16384
    if (blockIdx.x == 0) bar[threadIdx.x] = 0u;   // 256 entries
}

// ---------------- normalize + cast to bf16 ----------------
__global__ __launch_bounds__(256) void normalize_kernel(
    const float* __restrict__ student, const float* __restrict__ teacher,
    unsigned short* __restrict__ Sn, unsigned short* __restrict__ Tn)
{
    int rowid  = blockIdx.x;
    int tensor = rowid >> 14;         // 0: student, 1: teacher
    int row    = rowid & 16383;
    const float* src = tensor ? teacher : student;
    unsigned short* dst = tensor ? Tn : Sn;
    const float4* p4 = (const float4*)(src + (size_t)row * DIM);
    int t = threadIdx.x;

    float4 a = p4[t];
    float4 b = p4[t + 256];
    float ss = a.x*a.x + a.y*a.y + a.z*a.z + a.w*a.w
             + b.x*b.x + b.y*b.y + b.z*b.z + b.w*b.w;
    #pragma unroll
    for (int m = 32; m; m >>= 1) ss += __shfl_xor(ss, m, 64);
    __shared__ float wss[4];
    if ((t & 63) == 0) wss[t >> 6] = ss;
    __syncthreads();
    float rn = 1.0f / fmaxf(sqrtf(wss[0] + wss[1] + wss[2] + wss[3]), 1e-12f);

    unsigned short o1[4], o2[4];
    o1[0] = f_to_bf16(a.x * rn); o1[1] = f_to_bf16(a.y * rn);
    o1[2] = f_to_bf16(a.z * rn); o1[3] = f_to_bf16(a.w * rn);
    o2[0] = f_to_bf16(b.x * rn); o2[1] = f_to_bf16(b.y * rn);
    o2[2] = f_to_bf16(b.z * rn); o2[3] = f_to_bf16(b.w * rn);
    unsigned short* d = dst + (size_t)row * DIM;
    *(uint2*)(d + 4*t)        = *(uint2*)o1;
    *(uint2*)(d + 1024 + 4*t) = *(uint2*)o2;
}

// ---------------- batched GEMM -> K = exp(-C/eps), bf16 ----------------
#define TM  128
#define BK  32
#define LDK 40

__global__ __launch_bounds__(256) void gemm_cost_kernel(
    const unsigned short* __restrict__ Tn, const unsigned short* __restrict__ Sn,
    unsigned short* __restrict__ Kmat)
{
    __shared__ unsigned short As[TM * LDK];
    __shared__ unsigned short Bs[TM * LDK];

    int bid  = blockIdx.x;
    int b    = bid >> 6;
    int tile = bid & 63;
    int tm0  = (tile >> 3) * TM;
    int tn0  = (tile & 7)  * TM;

    const unsigned short* Ab = Tn + (size_t)b * SEQ * DIM;
    const unsigned short* Bb = Sn + (size_t)b * SEQ * DIM;

    int t    = threadIdx.x;
    int w    = t >> 6;
    int l    = t & 63;
    int mq   = (w >> 1) * 64;
    int nq   = (w & 1)  * 64;
    int lrow = l & 15;
    int kg   = l >> 4;

    int srow = t >> 2;
    int sseg = t & 3;

    f32x4 acc[4][4];
    #pragma unroll
    for (int i = 0; i < 4; i++)
        #pragma unroll
        for (int j = 0; j < 4; j++)
            acc[i][j] = (f32x4){0.f, 0.f, 0.f, 0.f};

    for (int k0 = 0; k0 < DIM; k0 += BK) {
        const int4 va0 = *(const int4*)(Ab + (size_t)(tm0 + srow)      * DIM + k0 + sseg * 8);
        const int4 va1 = *(const int4*)(Ab + (size_t)(tm0 + srow + 64) * DIM + k0 + sseg * 8);
        const int4 vb0 = *(const int4*)(Bb + (size_t)(tn0 + srow)      * DIM + k0 + sseg * 8);
        const int4 vb1 = *(const int4*)(Bb + (size_t)(tn0 + srow + 64) * DIM + k0 + sseg * 8);
        __syncthreads();
        *(int4*)&As[(srow)      * LDK + sseg * 8] = va0;
        *(int4*)&As[(srow + 64) * LDK + sseg * 8] = va1;
        *(int4*)&Bs[(srow)      * LDK + sseg * 8] = vb0;
        *(int4*)&Bs[(srow + 64) * LDK + sseg * 8] = vb1;
        __syncthreads();

        bf16x8 af[4], bfr[4];
        #pragma unroll
        for (int i = 0; i < 4; i++)
            af[i] = *(const bf16x8*)&As[(mq + i * 16 + lrow) * LDK + kg * 8];
        #pragma unroll
        for (int j = 0; j < 4; j++)
            bfr[j] = *(const bf16x8*)&Bs[(nq + j * 16 + lrow) * LDK + kg * 8];
        #pragma unroll
        for (int i = 0; i < 4; i++)
            #pragma unroll
            for (int j = 0; j < 4; j++)
                acc[i][j] = __builtin_amdgcn_mfma_f32_16x16x32_bf16(af[i], bfr[j], acc[i][j], 0, 0, 0);
    }

    unsigned short* Kb = Kmat + ((size_t)b << 20);
    #pragma unroll
    for (int i = 0; i < 4; i++) {
        #pragma unroll
        for (int j = 0; j < 4; j++) {
            int gcol = tn0 + nq + j * 16 + lrow;
            #pragma unroll
            for (int r = 0; r < 4; r++) {
                int grow = tm0 + mq + i * 16 + kg * 4 + r;
                float cosv = acc[i][j][r];
                float cost = 0.5f - 0.5f * cosv;
                Kb[((size_t)grow << 10) + gcol] = f_to_bf16(__expf(-cost * INV_EPS));
            }
        }
    }
}

// ---------------- persistent Sinkhorn + fused loss ----------------
// 256 blocks x 512 threads. batch b -> 16 blocks, all with idx&7 == b&7 (XCD-pinned).
__device__ inline void batch_barrier(unsigned int* barp, unsigned int tgt) {
    __threadfence();
    __syncthreads();
    if (threadIdx.x == 0) {
        __hip_atomic_fetch_add(barp, 1u, __ATOMIC_RELEASE, __HIP_MEMORY_SCOPE_AGENT);
        while (__hip_atomic_load(barp, __ATOMIC_ACQUIRE, __HIP_MEMORY_SCOPE_AGENT) < tgt)
            __builtin_amdgcn_s_sleep(1);
    }
    __syncthreads();
    __threadfence();
}

__global__ __launch_bounds__(512) void sinkhorn_persistent(
    const unsigned short* __restrict__ Kmat,
    float* __restrict__ u, float* __restrict__ v,
    unsigned int* __restrict__ bar, float* __restrict__ partials)
{
    __shared__ float xlds[1024];
    __shared__ float part[8][64];

    int idx   = blockIdx.x;
    int xr    = idx & 7;
    int sl    = idx >> 3;              // 0..31
    int b     = xr + ((sl >> 4) << 3); // 0..15, b&7 == idx&7
    int slice = sl & 15;               // 0..15

    const unsigned short* Kb = Kmat + ((size_t)b << 20);
    float* ub = u + (b << 10);
    float* vb = v + (b << 10);
    unsigned int* barp = bar + b * 16; // 64B-padded counters

    int t    = threadIdx.x;
    int lane = t & 63;
    int grp  = t >> 6;                 // 0..7
    int r0   = slice << 6;             // this block's 64 rows AND 64 cols

    unsigned int tgt = 0;

    for (int iter = 0; iter < N_ITER; iter++) {
        // ---- stage v -> LDS ----
        if (t < 256) *(float4*)&xlds[t * 4] = *(const float4*)&vb[t * 4];
        __syncthreads();

        // ---- row pass: u_i = (1/1024) / sum_j K_ij v_j ----
        {
            int row = r0 + lane;
            const unsigned short* kr = Kb + ((size_t)row << 10) + (grp << 7);
            const float* vl = &xlds[grp << 7];
            float s0 = 0.f, s1 = 0.f;
            #pragma unroll
            for (int jj = 0; jj < 128; jj += 8) {
                int4 kv = *(const int4*)(kr + jj);
                const unsigned short* ks = (const unsigned short*)&kv;
                s0 += bf16_to_f(ks[0]) * vl[jj + 0];
                s1 += bf16_to_f(ks[1]) * vl[jj + 1];
                s0 += bf16_to_f(ks[2]) * vl[jj + 2];
                s1 += bf16_to_f(ks[3]) * vl[jj + 3];
                s0 += bf16_to_f(ks[4]) * vl[jj + 4];
                s1 += bf16_to_f(ks[5]) * vl[jj + 5];
                s0 += bf16_to_f(ks[6]) * vl[jj + 6];
                s1 += bf16_to_f(ks[7]) * vl[jj + 7];
            }
            part[grp][lane] = s0 + s1;
        }
        __syncthreads();
        if (t < 64) {
            float tot = 0.f;
            #pragma unroll
            for (int g = 0; g < 8; g++) tot += part[g][t];
            ub[r0 + t] = (1.0f / 1024.0f) / tot;
        }
        tgt += 16; batch_barrier(barp, tgt);

        // ---- stage u -> LDS ----
        if (t < 256) *(float4*)&xlds[t * 4] = *(const float4*)&ub[t * 4];
        __syncthreads();

        // ---- col pass: v_j = (1/1024) / sum_i K_ij u_i ----
        {
            int col = r0 + lane;
            int i0  = grp << 7;
            const unsigned short* kc = Kb + ((size_t)i0 << 10) + col;
            float s0 = 0.f, s1 = 0.f;
            #pragma unroll 8
            for (int i = 0; i < 128; i += 2) {
                s0 += bf16_to_f(kc[(size_t)i << 10])       * xlds[i0 + i];
                s1 += bf16_to_f(kc[(size_t)(i + 1) << 10]) * xlds[i0 + i + 1];
            }
            part[grp][lane] = s0 + s1;
        }
        __syncthreads();
        if (t < 64) {
            float tot = 0.f;
            #pragma unroll
            for (int g = 0; g < 8; g++) tot += part[g][t];
            vb[r0 + t] = (1.0f / 1024.0f) / tot;
        }
        tgt += 16; batch_barrier(barp, tgt);
    }

    // ---- fused loss: sum_ij u_i K_ij v_j * (-eps ln K_ij) over this block's rows ----
    if (t < 256) *(float4*)&xlds[t * 4] = *(const float4*)&vb[t * 4];
    __syncthreads();
    {
        int row = r0 + lane;
        float ui = ub[row];
        const unsigned short* kr = Kb + ((size_t)row << 10) + (grp << 7);
        const float* vl = &xlds[grp << 7];
        float acc = 0.f;
        #pragma unroll 8
        for (int jj = 0; jj < 128; jj++) {
            float kf = bf16_to_f(kr[jj]);
            float C  = -EPS_F * __logf(kf);
            acc += kf * vl[jj] * C;
        }
        part[grp][lane] = acc * ui;
    }
    __syncthreads();
    if (t < 64) {
        float tot = 0.f;
        #pragma unroll
        for (int g = 0; g < 8; g++) tot += part[g][t];
        #pragma unroll
        for (int m = 32; m; m >>= 1) tot += __shfl_xor(tot, m, 64);
        if (t == 0) partials[idx] = tot;
    }
}

// ---------------- final reduce: 256 partials -> mean over 16 batches ----------------
__global__ __launch_bounds__(256) void loss_final(
    const float* __restrict__ partials, float* __restrict__ out)
{
    int t = threadIdx.x;
    float s = partials[t];
    #pragma unroll
    for (int m = 32; m; m >>= 1) s += __shfl_xor(s, m, 64);
    __shared__ float wp[4];
    if ((t & 63) == 0) wp[t >> 6] = s;
    __syncthreads();
    if (t == 0) out[0] = (wp[0] + wp[1] + wp[2] + wp[3]) * (1.0f / 16.0f);
}

extern "C" void kernel_launch(void* const* d_in, const int* in_sizes, int n_in,
                              void* d_out, int out_size, void* d_ws, size_t ws_size,
                              hipStream_t stream) {
    const float* student = (const float*)d_in[0];
    const float* teacher = (const float*)d_in[1];
    float* out = (float*)d_out;
    char* ws = (char*)d_ws;

    // ws layout (bytes)
    unsigned short* Tn   = (unsigned short*)(ws);                     // 64 MB
    unsigned short* Sn   = (unsigned short*)(ws + 67108864);          // 64 MB
    unsigned short* Kmat = (unsigned short*)(ws + 134217728);         // 32 MB
    float*        u        = (float*)(ws + 167772160);                // 64 KB
    float*        v        = (float*)(ws + 167772160 + 65536);        // 64 KB
    unsigned int* bar      = (unsigned int*)(ws + 167772160 + 131072);// 1 KB (256 uints)
    float*        partials = (float*)(ws + 167772160 + 132096);       // 1 KB (256 floats)

    hipLaunchKernelGGL(init_uvbar, dim3(64), dim3(256), 0, stream, v, bar);
    hipLaunchKernelGGL(normalize_kernel, dim3(32768), dim3(256), 0, stream,
                       student, teacher, Sn, Tn);
    hipLaunchKernelGGL(gemm_cost_kernel, dim3(1024), dim3(256), 0, stream, Tn, Sn, Kmat);
    hipLaunchKernelGGL(sinkhorn_persistent, dim3(256), dim3(512), 0, stream,
                       Kmat, u, v, bar, partials);
    hipLaunchKernelGGL(loss_final, dim3(1), dim3(256), 0, stream, partials, out);
}

// Round 3
// 1164.465 us; speedup vs baseline: 11.9449x; 11.9449x over previous
//
#include <hip/hip_runtime.h>
#include <math.h>

#define BATCH 16
#define SEQ   1024
#define DIM   2048
#define EPS_F 0.1f
#define INV_EPS 10.0f
#define N_ITER 100

typedef short bf16x8 __attribute__((ext_vector_type(8)));
typedef float f32x4  __attribute__((ext_vector_type(4)));

__device__ inline float blo(unsigned int x) { return __uint_as_float(x << 16); }
__device__ inline float bhi(unsigned int x) { return __uint_as_float(x & 0xffff0000u); }

__device__ inline unsigned short f_to_bf16(float f) {
    unsigned int x = __float_as_uint(f);
    unsigned int lsb = (x >> 16) & 1u;
    x += 0x7fffu + lsb;               // round-to-nearest-even
    return (unsigned short)(x >> 16);
}

// ---------------- init: t buffers = 0, flags = 0 ----------------
// tbuf: 16 batches * 4 rotating buffers * 1024 floats = 65536 floats
__global__ void init_state(float* __restrict__ tbuf, unsigned int* __restrict__ flags) {
    int i = blockIdx.x * 256 + threadIdx.x;   // grid 64*256 = 16384
    ((float4*)tbuf)[i] = (float4){0.f, 0.f, 0.f, 0.f};
    if (i < 1024) flags[i] = 0u;
}

// ---------------- normalize + cast to bf16 ----------------
__global__ __launch_bounds__(256) void normalize_kernel(
    const float* __restrict__ student, const float* __restrict__ teacher,
    unsigned short* __restrict__ Sn, unsigned short* __restrict__ Tn)
{
    int rowid  = blockIdx.x;
    int tensor = rowid >> 14;         // 0: student, 1: teacher
    int row    = rowid & 16383;
    const float* src = tensor ? teacher : student;
    unsigned short* dst = tensor ? Tn : Sn;
    const float4* p4 = (const float4*)(src + (size_t)row * DIM);
    int t = threadIdx.x;

    float4 a = p4[t];
    float4 b = p4[t + 256];
    float ss = a.x*a.x + a.y*a.y + a.z*a.z + a.w*a.w
             + b.x*b.x + b.y*b.y + b.z*b.z + b.w*b.w;
    #pragma unroll
    for (int m = 32; m; m >>= 1) ss += __shfl_xor(ss, m, 64);
    __shared__ float wss[4];
    if ((t & 63) == 0) wss[t >> 6] = ss;
    __syncthreads();
    float rn = 1.0f / fmaxf(sqrtf(wss[0] + wss[1] + wss[2] + wss[3]), 1e-12f);

    unsigned short o1[4], o2[4];
    o1[0] = f_to_bf16(a.x * rn); o1[1] = f_to_bf16(a.y * rn);
    o1[2] = f_to_bf16(a.z * rn); o1[3] = f_to_bf16(a.w * rn);
    o2[0] = f_to_bf16(b.x * rn); o2[1] = f_to_bf16(b.y * rn);
    o2[2] = f_to_bf16(b.z * rn); o2[3] = f_to_bf16(b.w * rn);
    unsigned short* d = dst + (size_t)row * DIM;
    *(uint2*)(d + 4*t)        = *(uint2*)o1;
    *(uint2*)(d + 1024 + 4*t) = *(uint2*)o2;
}

// ---------------- batched GEMM -> K = exp(-C/eps), bf16 ----------------
#define TM  128
#define BK  32
#define LDK 40

__global__ __launch_bounds__(256) void gemm_cost_kernel(
    const unsigned short* __restrict__ Tn, const unsigned short* __restrict__ Sn,
    unsigned short* __restrict__ Kmat)
{
    __shared__ unsigned short As[TM * LDK];
    __shared__ unsigned short Bs[TM * LDK];

    int bid  = blockIdx.x;
    int b    = bid >> 6;
    int tile = bid & 63;
    int tm0  = (tile >> 3) * TM;
    int tn0  = (tile & 7)  * TM;

    const unsigned short* Ab = Tn + (size_t)b * SEQ * DIM;
    const unsigned short* Bb = Sn + (size_t)b * SEQ * DIM;

    int t    = threadIdx.x;
    int w    = t >> 6;
    int l    = t & 63;
    int mq   = (w >> 1) * 64;
    int nq   = (w & 1)  * 64;
    int lrow = l & 15;
    int kg   = l >> 4;

    int srow = t >> 2;
    int sseg = t & 3;

    f32x4 acc[4][4];
    #pragma unroll
    for (int i = 0; i < 4; i++)
        #pragma unroll
        for (int j = 0; j < 4; j++)
            acc[i][j] = (f32x4){0.f, 0.f, 0.f, 0.f};

    for (int k0 = 0; k0 < DIM; k0 += BK) {
        const int4 va0 = *(const int4*)(Ab + (size_t)(tm0 + srow)      * DIM + k0 + sseg * 8);
        const int4 va1 = *(const int4*)(Ab + (size_t)(tm0 + srow + 64) * DIM + k0 + sseg * 8);
        const int4 vb0 = *(const int4*)(Bb + (size_t)(tn0 + srow)      * DIM + k0 + sseg * 8);
        const int4 vb1 = *(const int4*)(Bb + (size_t)(tn0 + srow + 64) * DIM + k0 + sseg * 8);
        __syncthreads();
        *(int4*)&As[(srow)      * LDK + sseg * 8] = va0;
        *(int4*)&As[(srow + 64) * LDK + sseg * 8] = va1;
        *(int4*)&Bs[(srow)      * LDK + sseg * 8] = vb0;
        *(int4*)&Bs[(srow + 64) * LDK + sseg * 8] = vb1;
        __syncthreads();

        bf16x8 af[4], bfr[4];
        #pragma unroll
        for (int i = 0; i < 4; i++)
            af[i] = *(const bf16x8*)&As[(mq + i * 16 + lrow) * LDK + kg * 8];
        #pragma unroll
        for (int j = 0; j < 4; j++)
            bfr[j] = *(const bf16x8*)&Bs[(nq + j * 16 + lrow) * LDK + kg * 8];
        #pragma unroll
        for (int i = 0; i < 4; i++)
            #pragma unroll
            for (int j = 0; j < 4; j++)
                acc[i][j] = __builtin_amdgcn_mfma_f32_16x16x32_bf16(af[i], bfr[j], acc[i][j], 0, 0, 0);
    }

    unsigned short* Kb = Kmat + ((size_t)b << 20);
    #pragma unroll
    for (int i = 0; i < 4; i++) {
        #pragma unroll
        for (int j = 0; j < 4; j++) {
            int gcol = tn0 + nq + j * 16 + lrow;
            #pragma unroll
            for (int r = 0; r < 4; r++) {
                int grow = tm0 + mq + i * 16 + kg * 4 + r;
                float cosv = acc[i][j][r];
                float cost = 0.5f - 0.5f * cosv;
                Kb[((size_t)grow << 10) + gcol] = f_to_bf16(__expf(-cost * INV_EPS));
            }
        }
    }
}

// ---------------- persistent Sinkhorn + fused loss ----------------
// 256 blocks x 512 threads, 1 block/CU capacity => always co-resident.
// Block owns a 64-ROW strip of one batch's K. One LLC barrier per iteration.
// All cross-block traffic via relaxed agent-scope (LLC) atomics: NO acquire/
// release fences => no L2 invalidation => K stays L2-resident.
__global__ __launch_bounds__(512) void sinkhorn_persistent(
    const unsigned short* __restrict__ Kmat,
    float* __restrict__ tbuf,          // [16][4][1024]
    unsigned int* __restrict__ flags,  // [16][64] (256B-padded counters)
    float* __restrict__ partials)      // [256]
{
    __shared__ float vlds[1024];
    __shared__ float part[64][66];
    __shared__ float red[64][9];
    __shared__ float ulds[64];

    int idx   = blockIdx.x;
    int b     = (idx & 7) | (((idx >> 3) & 1) << 3);  // idx%8 == b%8 : XCD-pinned
    int slice = idx >> 4;                             // 0..15
    const unsigned short* Kb = Kmat + ((size_t)b << 20);
    float* tb = tbuf + (b << 12);
    unsigned int* flag = flags + b * 64;

    int t    = threadIdx.x;
    int lane = t & 63;
    int w    = t >> 6;
    int r0   = slice << 6;          // this block's 64 rows (and its 64-col zero-slice)

    vlds[t] = 1.0f; vlds[t + 512] = 1.0f;   // v0 = 1
    __syncthreads();

    unsigned int tgt = 0;
    for (int iter = 0; iter < N_ITER; iter++) {
        // ---- sweep 1: u_i = (1/1024) / sum_j K_ij v_j  (rows r0..r0+63) ----
        float4 v0 = *(const float4*)&vlds[lane * 16];
        float4 v1 = *(const float4*)&vlds[lane * 16 + 4];
        float4 v2 = *(const float4*)&vlds[lane * 16 + 8];
        float4 v3 = *(const float4*)&vlds[lane * 16 + 12];
        #pragma unroll
        for (int rr = 0; rr < 8; rr++) {
            int row = r0 + w * 8 + rr;
            const unsigned int* kp = (const unsigned int*)(Kb + ((size_t)row << 10) + (lane << 4));
            unsigned int k0 = kp[0], k1 = kp[1], k2 = kp[2], k3 = kp[3];
            unsigned int k4 = kp[4], k5 = kp[5], k6 = kp[6], k7 = kp[7];
            float s = 0.f;
            s = fmaf(blo(k0), v0.x, s); s = fmaf(bhi(k0), v0.y, s);
            s = fmaf(blo(k1), v0.z, s); s = fmaf(bhi(k1), v0.w, s);
            s = fmaf(blo(k2), v1.x, s); s = fmaf(bhi(k2), v1.y, s);
            s = fmaf(blo(k3), v1.z, s); s = fmaf(bhi(k3), v1.w, s);
            s = fmaf(blo(k4), v2.x, s); s = fmaf(bhi(k4), v2.y, s);
            s = fmaf(blo(k5), v2.z, s); s = fmaf(bhi(k5), v2.w, s);
            s = fmaf(blo(k6), v3.x, s); s = fmaf(bhi(k6), v3.y, s);
            s = fmaf(blo(k7), v3.z, s); s = fmaf(bhi(k7), v3.w, s);
            part[w * 8 + rr][lane] = s;
        }
        __syncthreads();
        {
            int rrow = t >> 3, seg = t & 7;
            float s = 0.f;
            #pragma unroll
            for (int k = 0; k < 8; k++) s += part[rrow][seg * 8 + k];
            red[rrow][seg] = s;
        }
        __syncthreads();
        if (t < 64) {
            float s = red[t][0] + red[t][1] + red[t][2] + red[t][3]
                    + red[t][4] + red[t][5] + red[t][6] + red[t][7];
            ulds[t] = (1.0f / 1024.0f) / s;
        }
        __syncthreads();

        // ---- sweep 2: t_j += sum_{i in strip} K_ij u_i  (cols 2t, 2t+1) ----
        float a0 = 0.f, a1 = 0.f;
        const unsigned short* kc = Kb + ((size_t)r0 << 10) + (t << 1);
        #pragma unroll 8
        for (int i = 0; i < 64; i++) {
            unsigned int kk = *(const unsigned int*)(kc + ((size_t)i << 10));
            float ui = ulds[i];
            a0 = fmaf(blo(kk), ui, a0);
            a1 = fmaf(bhi(kk), ui, a1);
        }
        int cur = iter & 3;
        float* tcur = tb + (cur << 10);
        atomicAdd(&tcur[t * 2],     a0);   // device-scope f32 RMW at LLC, relaxed
        atomicAdd(&tcur[t * 2 + 1], a1);
        // zero the buffer used at iter+2 (own 64-col slice); LLC atomic store
        if (t < 64)
            __hip_atomic_store(&tb[(((iter + 2) & 3) << 10) + r0 + t], 0.0f,
                               __ATOMIC_RELAXED, __HIP_MEMORY_SCOPE_AGENT);
        __syncthreads();   // implicit per-wave s_waitcnt vmcnt(0): all atomics at LLC

        // ---- single LLC barrier per iteration ----
        tgt += 16;
        if (t == 0) {
            __hip_atomic_fetch_add(flag, 1u, __ATOMIC_RELAXED, __HIP_MEMORY_SCOPE_AGENT);
            while (__hip_atomic_load(flag, __ATOMIC_RELAXED, __HIP_MEMORY_SCOPE_AGENT) < tgt)
                __builtin_amdgcn_s_sleep(2);
        }
        __syncthreads();

        // ---- read t (LLC), compute v redundantly, stage to LDS ----
        float t0 = __hip_atomic_load(&tcur[t * 2],     __ATOMIC_RELAXED, __HIP_MEMORY_SCOPE_AGENT);
        float t1 = __hip_atomic_load(&tcur[t * 2 + 1], __ATOMIC_RELAXED, __HIP_MEMORY_SCOPE_AGENT);
        vlds[t * 2]     = (1.0f / 1024.0f) / t0;
        vlds[t * 2 + 1] = (1.0f / 1024.0f) / t1;
        __syncthreads();
    }

    // ---- fused loss over strip: sum_ij u_i K_ij v_j * (-eps ln K_ij) ----
    {
        float4 v0 = *(const float4*)&vlds[lane * 16];
        float4 v1 = *(const float4*)&vlds[lane * 16 + 4];
        float4 v2 = *(const float4*)&vlds[lane * 16 + 8];
        float4 v3 = *(const float4*)&vlds[lane * 16 + 12];
        float vreg[16] = {v0.x, v0.y, v0.z, v0.w, v1.x, v1.y, v1.z, v1.w,
                          v2.x, v2.y, v2.z, v2.w, v3.x, v3.y, v3.z, v3.w};
        #pragma unroll
        for (int rr = 0; rr < 8; rr++) {
            int row = r0 + w * 8 + rr;
            const unsigned int* kp = (const unsigned int*)(Kb + ((size_t)row << 10) + (lane << 4));
            float s = 0.f;
            #pragma unroll
            for (int q = 0; q < 8; q++) {
                unsigned int kk = kp[q];
                float klo = blo(kk), khi = bhi(kk);
                float clo = -EPS_F * __logf(klo);
                float chi = -EPS_F * __logf(khi);
                s = fmaf(klo * vreg[2 * q],     clo, s);
                s = fmaf(khi * vreg[2 * q + 1], chi, s);
            }
            part[w * 8 + rr][lane] = s;
        }
        __syncthreads();
        {
            int rrow = t >> 3, seg = t & 7;
            float s = 0.f;
            #pragma unroll
            for (int k = 0; k < 8; k++) s += part[rrow][seg * 8 + k];
            red[rrow][seg] = s;
        }
        __syncthreads();
        if (t < 64) {
            float rl = (red[t][0] + red[t][1] + red[t][2] + red[t][3]
                      + red[t][4] + red[t][5] + red[t][6] + red[t][7]) * ulds[t];
            #pragma unroll
            for (int m = 32; m; m >>= 1) rl += __shfl_xor(rl, m, 64);
            if (t == 0) partials[idx] = rl;
        }
    }
}

// ---------------- final reduce: 256 partials -> mean over 16 batches ----------------
__global__ __launch_bounds__(256) void loss_final(
    const float* __restrict__ partials, float* __restrict__ out)
{
    int t = threadIdx.x;
    float s = partials[t];
    #pragma unroll
    for (int m = 32; m; m >>= 1) s += __shfl_xor(s, m, 64);
    __shared__ float wp[4];
    if ((t & 63) == 0) wp[t >> 6] = s;
    __syncthreads();
    if (t == 0) out[0] = (wp[0] + wp[1] + wp[2] + wp[3]) * (1.0f / 16.0f);
}

extern "C" void kernel_launch(void* const* d_in, const int* in_sizes, int n_in,
                              void* d_out, int out_size, void* d_ws, size_t ws_size,
                              hipStream_t stream) {
    const float* student = (const float*)d_in[0];
    const float* teacher = (const float*)d_in[1];
    float* out = (float*)d_out;
    char* ws = (char*)d_ws;

    // ws layout (bytes)
    unsigned short* Tn   = (unsigned short*)(ws);                     // 64 MB
    unsigned short* Sn   = (unsigned short*)(ws + 67108864);          // 64 MB
    unsigned short* Kmat = (unsigned short*)(ws + 134217728);         // 32 MB
    float*        tbuf     = (float*)(ws + 167772160);                // 256 KB
    unsigned int* flags    = (unsigned int*)(ws + 167772160 + 262144);// 4 KB
    float*        partials = (float*)(ws + 167772160 + 266240);       // 1 KB

    hipLaunchKernelGGL(init_state, dim3(64), dim3(256), 0, stream, tbuf, flags);
    hipLaunchKernelGGL(normalize_kernel, dim3(32768), dim3(256), 0, stream,
                       student, teacher, Sn, Tn);
    hipLaunchKernelGGL(gemm_cost_kernel, dim3(1024), dim3(256), 0, stream, Tn, Sn, Kmat);
    hipLaunchKernelGGL(sinkhorn_persistent, dim3(256), dim3(512), 0, stream,
                       Kmat, tbuf, flags, partials);
    hipLaunchKernelGGL(loss_final, dim3(1), dim3(256), 0, stream, partials, out);
}

// Round 4
// 874.924 us; speedup vs baseline: 15.8979x; 1.3309x over previous
//
#include <hip/hip_runtime.h>
#include <math.h>

#define BATCH 16
#define SEQ   1024
#define DIM   2048
#define EPS_F 0.1f
#define INV_EPS 10.0f
#define N_ITER 100

typedef short bf16x8 __attribute__((ext_vector_type(8)));
typedef float f32x4  __attribute__((ext_vector_type(4)));

__device__ inline float blo(unsigned int x) { return __uint_as_float(x << 16); }
__device__ inline float bhi(unsigned int x) { return __uint_as_float(x & 0xffff0000u); }

__device__ inline unsigned short f_to_bf16(float f) {
    unsigned int x = __float_as_uint(f);
    unsigned int lsb = (x >> 16) & 1u;
    x += 0x7fffu + lsb;               // round-to-nearest-even
    return (unsigned short)(x >> 16);
}

// ---------------- init: t buffers = 0, flags = 0 ----------------
__global__ void init_state(float* __restrict__ tbuf, unsigned int* __restrict__ flags) {
    int i = blockIdx.x * 256 + threadIdx.x;   // grid 64*256 = 16384
    ((float4*)tbuf)[i] = (float4){0.f, 0.f, 0.f, 0.f};
    if (i < 1024) flags[i] = 0u;
}

// ---------------- normalize + cast to bf16 ----------------
__global__ __launch_bounds__(256) void normalize_kernel(
    const float* __restrict__ student, const float* __restrict__ teacher,
    unsigned short* __restrict__ Sn, unsigned short* __restrict__ Tn)
{
    int rowid  = blockIdx.x;
    int tensor = rowid >> 14;
    int row    = rowid & 16383;
    const float* src = tensor ? teacher : student;
    unsigned short* dst = tensor ? Tn : Sn;
    const float4* p4 = (const float4*)(src + (size_t)row * DIM);
    int t = threadIdx.x;

    float4 a = p4[t];
    float4 b = p4[t + 256];
    float ss = a.x*a.x + a.y*a.y + a.z*a.z + a.w*a.w
             + b.x*b.x + b.y*b.y + b.z*b.z + b.w*b.w;
    #pragma unroll
    for (int m = 32; m; m >>= 1) ss += __shfl_xor(ss, m, 64);
    __shared__ float wss[4];
    if ((t & 63) == 0) wss[t >> 6] = ss;
    __syncthreads();
    float rn = 1.0f / fmaxf(sqrtf(wss[0] + wss[1] + wss[2] + wss[3]), 1e-12f);

    unsigned short o1[4], o2[4];
    o1[0] = f_to_bf16(a.x * rn); o1[1] = f_to_bf16(a.y * rn);
    o1[2] = f_to_bf16(a.z * rn); o1[3] = f_to_bf16(a.w * rn);
    o2[0] = f_to_bf16(b.x * rn); o2[1] = f_to_bf16(b.y * rn);
    o2[2] = f_to_bf16(b.z * rn); o2[3] = f_to_bf16(b.w * rn);
    unsigned short* d = dst + (size_t)row * DIM;
    *(uint2*)(d + 4*t)        = *(uint2*)o1;
    *(uint2*)(d + 1024 + 4*t) = *(uint2*)o2;
}

// ---------------- batched GEMM -> K = exp(-C/eps), bf16 ----------------
#define TM  128
#define BK  32
#define LDK 40

__global__ __launch_bounds__(256) void gemm_cost_kernel(
    const unsigned short* __restrict__ Tn, const unsigned short* __restrict__ Sn,
    unsigned short* __restrict__ Kmat)
{
    __shared__ unsigned short As[TM * LDK];
    __shared__ unsigned short Bs[TM * LDK];

    int bid  = blockIdx.x;
    int b    = bid >> 6;
    int tile = bid & 63;
    int tm0  = (tile >> 3) * TM;
    int tn0  = (tile & 7)  * TM;

    const unsigned short* Ab = Tn + (size_t)b * SEQ * DIM;
    const unsigned short* Bb = Sn + (size_t)b * SEQ * DIM;

    int t    = threadIdx.x;
    int w    = t >> 6;
    int l    = t & 63;
    int mq   = (w >> 1) * 64;
    int nq   = (w & 1)  * 64;
    int lrow = l & 15;
    int kg   = l >> 4;

    int srow = t >> 2;
    int sseg = t & 3;

    f32x4 acc[4][4];
    #pragma unroll
    for (int i = 0; i < 4; i++)
        #pragma unroll
        for (int j = 0; j < 4; j++)
            acc[i][j] = (f32x4){0.f, 0.f, 0.f, 0.f};

    for (int k0 = 0; k0 < DIM; k0 += BK) {
        const int4 va0 = *(const int4*)(Ab + (size_t)(tm0 + srow)      * DIM + k0 + sseg * 8);
        const int4 va1 = *(const int4*)(Ab + (size_t)(tm0 + srow + 64) * DIM + k0 + sseg * 8);
        const int4 vb0 = *(const int4*)(Bb + (size_t)(tn0 + srow)      * DIM + k0 + sseg * 8);
        const int4 vb1 = *(const int4*)(Bb + (size_t)(tn0 + srow + 64) * DIM + k0 + sseg * 8);
        __syncthreads();
        *(int4*)&As[(srow)      * LDK + sseg * 8] = va0;
        *(int4*)&As[(srow + 64) * LDK + sseg * 8] = va1;
        *(int4*)&Bs[(srow)      * LDK + sseg * 8] = vb0;
        *(int4*)&Bs[(srow + 64) * LDK + sseg * 8] = vb1;
        __syncthreads();

        bf16x8 af[4], bfr[4];
        #pragma unroll
        for (int i = 0; i < 4; i++)
            af[i] = *(const bf16x8*)&As[(mq + i * 16 + lrow) * LDK + kg * 8];
        #pragma unroll
        for (int j = 0; j < 4; j++)
            bfr[j] = *(const bf16x8*)&Bs[(nq + j * 16 + lrow) * LDK + kg * 8];
        #pragma unroll
        for (int i = 0; i < 4; i++)
            #pragma unroll
            for (int j = 0; j < 4; j++)
                acc[i][j] = __builtin_amdgcn_mfma_f32_16x16x32_bf16(af[i], bfr[j], acc[i][j], 0, 0, 0);
    }

    unsigned short* Kb = Kmat + ((size_t)b << 20);
    #pragma unroll
    for (int i = 0; i < 4; i++) {
        #pragma unroll
        for (int j = 0; j < 4; j++) {
            int gcol = tn0 + nq + j * 16 + lrow;
            #pragma unroll
            for (int r = 0; r < 4; r++) {
                int grow = tm0 + mq + i * 16 + kg * 4 + r;
                float cosv = acc[i][j][r];
                float cost = 0.5f - 0.5f * cosv;
                Kb[((size_t)grow << 10) + gcol] = f_to_bf16(__expf(-cost * INV_EPS));
            }
        }
    }
}

// ---------------- persistent Sinkhorn + fused loss ----------------
// 256 blocks x 512 threads. Block owns a 64-row strip of one batch.
// SINGLE pass over K per iteration: row fragment is loaded once, used for
// the row dot (u_i via in-wave butterfly broadcast) AND immediately for the
// column partials t_j += K_ij u_i. Cross-block: relaxed LLC atomics only.
__global__ __launch_bounds__(512) void sinkhorn_persistent(
    const unsigned short* __restrict__ Kmat,
    float* __restrict__ tbuf,          // [16][4][1024]
    unsigned int* __restrict__ flags,  // [16][64]
    float* __restrict__ partials)      // [256]
{
    __shared__ float part[8 * 1024];   // per-wave column partials
    __shared__ float vsw[1024];        // v, swizzled: v[c] at (c&15)*64 + (c>>4)
    __shared__ float ulds[64];
    __shared__ float wlds[8];

    int idx   = blockIdx.x;
    int b     = (idx & 7) | (((idx >> 3) & 1) << 3);  // idx%8 == b%8 : XCD-pinned
    int slice = idx >> 4;                             // 0..15
    const unsigned short* Kb = Kmat + ((size_t)b << 20);
    float* tb = tbuf + (b << 12);
    unsigned int* flag = flags + b * 64;

    int t    = threadIdx.x;
    int lane = t & 63;
    int w    = t >> 6;                 // wave 0..7
    int r0   = slice << 6;             // this block's 64 rows (also its 64-col zero-slice)

    vsw[t] = 1.0f; vsw[t + 512] = 1.0f;     // v0 = 1 (swizzle of ones is ones)
    __syncthreads();

    unsigned int tgt = 0;
    for (int iter = 0; iter < N_ITER; iter++) {
        // vreg[k] = v[lane*16 + k]  — conflict-free swizzled loads
        float vreg[16];
        #pragma unroll
        for (int k = 0; k < 16; k++) vreg[k] = vsw[k * 64 + lane];

        float tacc[16];
        #pragma unroll
        for (int k = 0; k < 16; k++) tacc[k] = 0.f;

        // ---- fused sweep over 8 rows: u_i then column partials ----
        #pragma unroll
        for (int rr = 0; rr < 8; rr++) {
            int row = r0 + w * 8 + rr;
            const unsigned int* kp = (const unsigned int*)(Kb + ((size_t)row << 10) + (lane << 4));
            unsigned int k0 = kp[0], k1 = kp[1], k2 = kp[2], k3 = kp[3];
            unsigned int k4 = kp[4], k5 = kp[5], k6 = kp[6], k7 = kp[7];
            float f0  = blo(k0), f1  = bhi(k0), f2  = blo(k1), f3  = bhi(k1);
            float f4  = blo(k2), f5  = bhi(k2), f6  = blo(k3), f7  = bhi(k3);
            float f8  = blo(k4), f9  = bhi(k4), f10 = blo(k5), f11 = bhi(k5);
            float f12 = blo(k6), f13 = bhi(k6), f14 = blo(k7), f15 = bhi(k7);
            float s = 0.f;
            s = fmaf(f0,  vreg[0],  s); s = fmaf(f1,  vreg[1],  s);
            s = fmaf(f2,  vreg[2],  s); s = fmaf(f3,  vreg[3],  s);
            s = fmaf(f4,  vreg[4],  s); s = fmaf(f5,  vreg[5],  s);
            s = fmaf(f6,  vreg[6],  s); s = fmaf(f7,  vreg[7],  s);
            s = fmaf(f8,  vreg[8],  s); s = fmaf(f9,  vreg[9],  s);
            s = fmaf(f10, vreg[10], s); s = fmaf(f11, vreg[11], s);
            s = fmaf(f12, vreg[12], s); s = fmaf(f13, vreg[13], s);
            s = fmaf(f14, vreg[14], s); s = fmaf(f15, vreg[15], s);
            #pragma unroll
            for (int m = 32; m; m >>= 1) s += __shfl_xor(s, m, 64);
            float ui = (1.0f / 1024.0f) / s;          // uniform across wave
            if (lane == 0) ulds[w * 8 + rr] = ui;
            tacc[0]  = fmaf(f0,  ui, tacc[0]);  tacc[1]  = fmaf(f1,  ui, tacc[1]);
            tacc[2]  = fmaf(f2,  ui, tacc[2]);  tacc[3]  = fmaf(f3,  ui, tacc[3]);
            tacc[4]  = fmaf(f4,  ui, tacc[4]);  tacc[5]  = fmaf(f5,  ui, tacc[5]);
            tacc[6]  = fmaf(f6,  ui, tacc[6]);  tacc[7]  = fmaf(f7,  ui, tacc[7]);
            tacc[8]  = fmaf(f8,  ui, tacc[8]);  tacc[9]  = fmaf(f9,  ui, tacc[9]);
            tacc[10] = fmaf(f10, ui, tacc[10]); tacc[11] = fmaf(f11, ui, tacc[11]);
            tacc[12] = fmaf(f12, ui, tacc[12]); tacc[13] = fmaf(f13, ui, tacc[13]);
            tacc[14] = fmaf(f14, ui, tacc[14]); tacc[15] = fmaf(f15, ui, tacc[15]);
        }
        // wave partials -> LDS
        #pragma unroll
        for (int k = 0; k < 16; k += 4)
            *(float4*)&part[w * 1024 + lane * 16 + k] =
                (float4){tacc[k], tacc[k+1], tacc[k+2], tacc[k+3]};
        __syncthreads();

        // reduce 8 waves, then LLC atomics (cols 2t, 2t+1)
        float a0 = 0.f, a1 = 0.f;
        #pragma unroll
        for (int g = 0; g < 8; g++) {
            float2 p = *(const float2*)&part[g * 1024 + t * 2];
            a0 += p.x; a1 += p.y;
        }
        int cur = iter & 3;
        float* tcur = tb + (cur << 10);
        atomicAdd(&tcur[t * 2],     a0);
        atomicAdd(&tcur[t * 2 + 1], a1);
        if (t < 64)
            __hip_atomic_store(&tb[(((iter + 2) & 3) << 10) + r0 + t], 0.0f,
                               __ATOMIC_RELAXED, __HIP_MEMORY_SCOPE_AGENT);
        __syncthreads();   // per-wave vmcnt(0): all atomics drained to LLC

        // ---- single LLC barrier per iteration ----
        tgt += 16;
        if (t == 0) {
            __hip_atomic_fetch_add(flag, 1u, __ATOMIC_RELAXED, __HIP_MEMORY_SCOPE_AGENT);
            while (__hip_atomic_load(flag, __ATOMIC_RELAXED, __HIP_MEMORY_SCOPE_AGENT) < tgt)
                __builtin_amdgcn_s_sleep(2);
        }
        __syncthreads();

        // ---- read t (LLC), compute v, store swizzled ----
        float t0 = __hip_atomic_load(&tcur[t * 2],     __ATOMIC_RELAXED, __HIP_MEMORY_SCOPE_AGENT);
        float t1 = __hip_atomic_load(&tcur[t * 2 + 1], __ATOMIC_RELAXED, __HIP_MEMORY_SCOPE_AGENT);
        int c0 = t * 2, c1 = t * 2 + 1;
        vsw[(c0 & 15) * 64 + (c0 >> 4)] = (1.0f / 1024.0f) / t0;
        vsw[(c1 & 15) * 64 + (c1 >> 4)] = (1.0f / 1024.0f) / t1;
        __syncthreads();
    }

    // ---- fused loss over strip: sum_ij u_i K_ij v_j * (-eps ln K_ij) ----
    {
        float vreg[16];
        #pragma unroll
        for (int k = 0; k < 16; k++) vreg[k] = vsw[k * 64 + lane];
        float wsum = 0.f;
        #pragma unroll
        for (int rr = 0; rr < 8; rr++) {
            int row = r0 + w * 8 + rr;
            const unsigned int* kp = (const unsigned int*)(Kb + ((size_t)row << 10) + (lane << 4));
            float s = 0.f;
            #pragma unroll
            for (int q = 0; q < 8; q++) {
                unsigned int kk = kp[q];
                float klo = blo(kk), khi = bhi(kk);
                float clo = -EPS_F * __logf(klo);
                float chi = -EPS_F * __logf(khi);
                s = fmaf(klo * vreg[2 * q],     clo, s);
                s = fmaf(khi * vreg[2 * q + 1], chi, s);
            }
            #pragma unroll
            for (int m = 32; m; m >>= 1) s += __shfl_xor(s, m, 64);
            if (lane == 0) wsum += s * ulds[w * 8 + rr];
        }
        if (lane == 0) wlds[w] = wsum;
    }
    __syncthreads();
    if (t == 0) {
        float s = 0.f;
        #pragma unroll
        for (int g = 0; g < 8; g++) s += wlds[g];
        partials[idx] = s;
    }
}

// ---------------- final reduce ----------------
__global__ __launch_bounds__(256) void loss_final(
    const float* __restrict__ partials, float* __restrict__ out)
{
    int t = threadIdx.x;
    float s = partials[t];
    #pragma unroll
    for (int m = 32; m; m >>= 1) s += __shfl_xor(s, m, 64);
    __shared__ float wp[4];
    if ((t & 63) == 0) wp[t >> 6] = s;
    __syncthreads();
    if (t == 0) out[0] = (wp[0] + wp[1] + wp[2] + wp[3]) * (1.0f / 16.0f);
}

extern "C" void kernel_launch(void* const* d_in, const int* in_sizes, int n_in,
                              void* d_out, int out_size, void* d_ws, size_t ws_size,
                              hipStream_t stream) {
    const float* student = (const float*)d_in[0];
    const float* teacher = (const float*)d_in[1];
    float* out = (float*)d_out;
    char* ws = (char*)d_ws;

    unsigned short* Tn   = (unsigned short*)(ws);                     // 64 MB
    unsigned short* Sn   = (unsigned short*)(ws + 67108864);          // 64 MB
    unsigned short* Kmat = (unsigned short*)(ws + 134217728);         // 32 MB
    float*        tbuf     = (float*)(ws + 167772160);                // 256 KB
    unsigned int* flags    = (unsigned int*)(ws + 167772160 + 262144);// 4 KB
    float*        partials = (float*)(ws + 167772160 + 266240);       // 1 KB

    hipLaunchKernelGGL(init_state, dim3(64), dim3(256), 0, stream, tbuf, flags);
    hipLaunchKernelGGL(normalize_kernel, dim3(32768), dim3(256), 0, stream,
                       student, teacher, Sn, Tn);
    hipLaunchKernelGGL(gemm_cost_kernel, dim3(1024), dim3(256), 0, stream, Tn, Sn, Kmat);
    hipLaunchKernelGGL(sinkhorn_persistent, dim3(256), dim3(512), 0, stream,
                       Kmat, tbuf, flags, partials);
    hipLaunchKernelGGL(loss_final, dim3(1), dim3(256), 0, stream, partials, out);
}